// Round 1
// baseline (209.313 us; speedup 1.0000x reference)
//
#include <hip/hip_runtime.h>

#define BB 16
#define HH 512
#define WW 512
#define CC 3
#define ROWLEN 1536   // W*C
#define KK 51
#define RR 25

// ---------------- K0: reduce 2D kernel to 1D weights (g[i] = row sum) -------
__global__ void k_weights(const float* __restrict__ k2d, float* __restrict__ g) {
    int i = threadIdx.x;
    if (i < KK) {
        float s = 0.f;
        for (int j = 0; j < KK; ++j) s += k2d[i * KK + j];
        g[i] = s;
    }
}

// ---------------- H-pass: 51-tap conv along w, per channel ------------------
// One block per (b,h) row. 192 threads. Row de-interleaved into 3 channel
// planes in LDS with 25-elem reflect halos. Each thread computes 8 consecutive
// pixels of one channel via a sliding window (float4 LDS reads).
template<bool U8>
__global__ __launch_bounds__(192) void k_hconv(const void* __restrict__ srcv,
                                               float* __restrict__ dst,
                                               const float* __restrict__ gsrc) {
    __shared__ __align__(16) float pl[3][564];   // 25 + 512 + 25 (+2 pad), 16B-aligned stride
    const int t = threadIdx.x;
    const int row = blockIdx.x;                  // b*512 + h
    const size_t rb = (size_t)row * ROWLEN;

    float gw[KK];
    #pragma unroll
    for (int i = 0; i < KK; ++i) gw[i] = gsrc[i];   // uniform -> s_load

    // ---- load row, de-interleave into planes ----
    if (U8) {
        const uint2 d = ((const uint2*)srcv)[row * 192 + t];    // 8 bytes
        #pragma unroll
        for (int k = 0; k < 8; ++k) {
            const int flat = t * 8 + k;
            const unsigned int word = (k < 4) ? d.x : d.y;
            const float v = (float)((word >> ((k & 3) * 8)) & 0xffu);
            pl[flat % 3][RR + flat / 3] = v;
        }
    } else {
        const float4 f0 = ((const float4*)srcv)[row * 384 + t];
        const float4 f1 = ((const float4*)srcv)[row * 384 + 192 + t];
        #pragma unroll
        for (int k = 0; k < 4; ++k) {
            const int fl0 = 4 * t + k;
            pl[fl0 % 3][RR + fl0 / 3] = (&f0.x)[k];
            const int fl1 = 768 + 4 * t + k;
            pl[fl1 % 3][RR + fl1 / 3] = (&f1.x)[k];
        }
    }
    __syncthreads();

    // ---- reflect halos (np.pad 'reflect': excludes edge) ----
    if (t < 150) {
        const int c2 = t / 50, k = t % 50;
        if (k < 25) pl[c2][k] = pl[c2][50 - k];            // x=k-25 -> src w=25-k
        else        pl[c2][512 + k] = pl[c2][535 - (k - 25)]; // x=512+k2 -> src w=510-k2
    }
    __syncthreads();

    // ---- compute: 8 consecutive pixels of one channel per thread ----
    const int c  = t >> 6;            // 0..2 (wave-uniform)
    const int w0 = (t & 63) << 3;     // 0,8,...,504
    float acc[8] = {0.f,0.f,0.f,0.f,0.f,0.f,0.f,0.f};
    const float* p = &pl[c][w0];      // padded tap j for output a is p[a + tap]
    #pragma unroll
    for (int jj = 0; jj < 15; ++jj) {
        const float4 v4 = *(const float4*)(p + 4 * jj);
        #pragma unroll
        for (int k = 0; k < 4; ++k) {
            const int j = 4 * jj + k;
            const float v = (&v4.x)[k];
            #pragma unroll
            for (int a = 0; a < 8; ++a) {
                const int tap = j - a;
                if (tap >= 0 && tap < KK) acc[a] += gw[tap] * v;
            }
        }
    }
    #pragma unroll
    for (int a = 0; a < 8; ++a)
        dst[rb + (size_t)(w0 + a) * 3 + c] = acc[a];
}

// ---------------- V-pass: 51-tap conv along h + fused epilogue --------------
// Tile: 64 flat columns x 64 output rows (+2*25 halo). 256 threads =
// 64 cols x 4 h-groups; each thread computes 16 outputs (sliding window).
// MODE 0: blur -> blurio (d_out as scratch), mask -> mask8.
// MODE 1: soft-mask; read img + blur (from blurio), write final to blurio.
#define HC 64
#define FW 64
#define HLOAD 114    // HC + 2*RR

template<int MODE>
__global__ __launch_bounds__(256) void k_vconv(const float* __restrict__ src,
                                               const float* __restrict__ img,
                                               float* blurio,
                                               unsigned char* __restrict__ mask8,
                                               const float* __restrict__ gsrc) {
    __shared__ __align__(16) float tile[HLOAD * FW];
    const int t   = threadIdx.x;
    const int col = t & 63;
    const int hg  = t >> 6;              // 0..3 (wave-uniform)
    const int bid = blockIdx.x;
    const int wcB = bid % 24;
    const int hB  = (bid / 24) & 7;
    const int b   = bid / 192;
    const int wc0 = wcB * 64;
    const int h0  = hB * 64;

    float gw[KK];
    #pragma unroll
    for (int i = 0; i < KK; ++i) gw[i] = gsrc[i];

    const size_t imgbase = (size_t)b * HH * ROWLEN;

    // ---- load tile with reflect on h ----
    for (int r = hg; r < HLOAD; r += 4) {
        int hs = h0 - RR + r;
        hs = hs < 0 ? -hs : hs;
        hs = hs > 511 ? 1022 - hs : hs;
        tile[r * FW + col] = src[imgbase + (size_t)hs * ROWLEN + wc0 + col];
    }
    __syncthreads();

    float acc[16];
    #pragma unroll
    for (int a = 0; a < 16; ++a) acc[a] = 0.f;
    #pragma unroll
    for (int j = 0; j < 66; ++j) {
        const float v = tile[(hg * 16 + j) * FW + col];
        #pragma unroll
        for (int a = 0; a < 16; ++a) {
            const int tap = j - a;
            if (tap >= 0 && tap < KK) acc[a] += gw[tap] * v;
        }
    }

    // ---- fused epilogue ----
    #pragma unroll
    for (int a = 0; a < 16; ++a) {
        const int hh = h0 + hg * 16 + a;
        const size_t idx = imgbase + (size_t)hh * ROWLEN + wc0 + col;
        const float x = img[idx];
        if (MODE == 0) {
            const float blur = acc[a];
            blurio[idx] = blur;
            mask8[idx] = (fabsf(x - blur) * 255.0f > 10.0f) ? (unsigned char)1
                                                            : (unsigned char)0;
        } else {
            const float bl = blurio[idx];                       // blur of img
            const float sharp = fminf(fmaxf(x + 0.5f * (x - bl), 0.f), 1.f);
            const float sm = acc[a];                            // soft mask
            blurio[idx] = x + sm * (sharp - x);                 // final output
        }
    }
}

// ---------------------------------------------------------------------------
extern "C" void kernel_launch(void* const* d_in, const int* in_sizes, int n_in,
                              void* d_out, int out_size, void* d_ws, size_t ws_size,
                              hipStream_t stream) {
    (void)in_sizes; (void)n_in; (void)out_size; (void)ws_size;
    const float* img = (const float*)d_in[0];
    const float* k2d = (const float*)d_in[1];
    float* out = (float*)d_out;

    char* ws = (char*)d_ws;
    float* g = (float*)ws;                                       // 51 floats
    float* tbuf = (float*)(ws + 256);                            // 50.33 MB
    unsigned char* mask8 =
        (unsigned char*)(ws + 256 + (size_t)BB * HH * ROWLEN * 4); // 12.58 MB

    const int nrows = BB * HH;            // 8192
    const int nvblk = BB * 8 * 24;        // 3072

    k_weights<<<1, 64, 0, stream>>>(k2d, g);
    // P1: H-blur img -> tbuf
    k_hconv<false><<<nrows, 192, 0, stream>>>((const void*)img, tbuf, g);
    // P2: V-blur tbuf -> blur (into d_out) + mask8
    k_vconv<0><<<nvblk, 256, 0, stream>>>(tbuf, img, out, mask8, g);
    // P3: H-blur mask8 -> tbuf
    k_hconv<true><<<nrows, 192, 0, stream>>>((const void*)mask8, tbuf, g);
    // P4: V-blur tbuf -> soft mask, fused blend -> d_out
    k_vconv<1><<<nvblk, 256, 0, stream>>>(tbuf, img, out, mask8, g);
}

// Round 2
// 182.948 us; speedup vs baseline: 1.1441x; 1.1441x over previous
//
#include <hip/hip_runtime.h>

#define BB 16
#define HH 512
#define WW 512
#define CC 3
#define ROWLEN 1536   // W*C
#define KK 51
#define RR 25

// ---------------- K0: reduce 2D kernel to 1D weights (g[i] = row sum) -------
__global__ void k_weights(const float* __restrict__ k2d, float* __restrict__ g) {
    int i = threadIdx.x;
    if (i < KK) {
        float s = 0.f;
        for (int j = 0; j < KK; ++j) s += k2d[i * KK + j];
        g[i] = s;
    }
}

// ---------------- H-pass: 51-tap conv along w, per channel ------------------
// One block per (b,h) row. 384 threads = 3 channels x 128 lanes.
// Row de-interleaved into 3 channel planes in LDS (stride 576 floats = 18x128B
// so 16B-chunk -> bank-group mapping is lane+jj: conflict-free b128 reads).
// Each thread computes 4 consecutive pixels of one channel (sliding window).
#define PSTRIDE 576
template<bool U8>
__global__ __launch_bounds__(384) void k_hconv(const void* __restrict__ srcv,
                                               float* __restrict__ dst,
                                               const float* __restrict__ gsrc) {
    __shared__ __align__(128) float pl[3][PSTRIDE];   // 25 + 512 + 25 used
    const int t = threadIdx.x;
    const int row = blockIdx.x;                  // b*512 + h
    const size_t rb = (size_t)row * ROWLEN;

    float gw[KK];
    #pragma unroll
    for (int i = 0; i < KK; ++i) gw[i] = gsrc[i];   // uniform -> scalar regs

    // ---- load row (1536 elems), de-interleave into planes ----
    if (U8) {
        const unsigned int d = ((const unsigned int*)srcv)[row * 384 + t]; // 4 bytes
        #pragma unroll
        for (int k = 0; k < 4; ++k) {
            const int flat = t * 4 + k;
            const float v = (float)((d >> (k * 8)) & 0xffu);
            pl[flat % 3][RR + flat / 3] = v;
        }
    } else {
        const float4 f0 = ((const float4*)srcv)[row * 384 + t];
        #pragma unroll
        for (int k = 0; k < 4; ++k) {
            const int fl = 4 * t + k;
            pl[fl % 3][RR + fl / 3] = (&f0.x)[k];
        }
    }
    __syncthreads();

    // ---- reflect halos (np.pad 'reflect': excludes edge) ----
    if (t < 150) {
        const int c2 = t / 50, k = t % 50;
        if (k < 25) pl[c2][k] = pl[c2][50 - k];               // x=k-25 -> src w=25-k
        else        pl[c2][512 + k] = pl[c2][535 - (k - 25)]; // x=512+k2 -> src w=510-k2
    }
    __syncthreads();

    // ---- compute: 4 consecutive pixels of one channel per thread ----
    const int c  = t >> 7;            // 0..2 (wave-uniform)
    const int l  = t & 127;
    const int w0 = l << 2;            // 0,4,...,508
    float acc[4] = {0.f, 0.f, 0.f, 0.f};
    const float* p = &pl[c][w0];      // padded tap j for output a is p[a + tap]
    #pragma unroll
    for (int jj = 0; jj < 14; ++jj) {
        const float4 v4 = *(const float4*)(p + 4 * jj);
        #pragma unroll
        for (int k = 0; k < 4; ++k) {
            const int j = 4 * jj + k;
            const float v = (&v4.x)[k];
            #pragma unroll
            for (int a = 0; a < 4; ++a) {
                const int tap = j - a;
                if (tap >= 0 && tap < KK) acc[a] += gw[tap] * v;
            }
        }
    }
    #pragma unroll
    for (int a = 0; a < 4; ++a)
        dst[rb + (size_t)(w0 + a) * 3 + c] = acc[a];
}

// ---------------- V-pass: 51-tap conv along h + fused epilogue --------------
// Tile: 64 flat columns x 64 output rows (+2*25 halo). 256 threads =
// 64 cols x 4 h-groups; each thread computes 16 outputs (sliding window).
// MODE 0: blur -> blurio (d_out as scratch), mask -> mask8.
// MODE 1: soft-mask; read img + blur (from blurio), write final to blurio.
#define HC 64
#define FW 64
#define HLOAD 114    // HC + 2*RR

template<int MODE>
__global__ __launch_bounds__(256) void k_vconv(const float* __restrict__ src,
                                               const float* __restrict__ img,
                                               float* blurio,
                                               unsigned char* __restrict__ mask8,
                                               const float* __restrict__ gsrc) {
    __shared__ __align__(16) float tile[HLOAD * FW];
    const int t   = threadIdx.x;
    const int col = t & 63;
    const int hg  = t >> 6;              // 0..3 (wave-uniform)
    const int bid = blockIdx.x;
    const int wcB = bid % 24;
    const int hB  = (bid / 24) & 7;
    const int b   = bid / 192;
    const int wc0 = wcB * 64;
    const int h0  = hB * 64;

    float gw[KK];
    #pragma unroll
    for (int i = 0; i < KK; ++i) gw[i] = gsrc[i];

    const size_t imgbase = (size_t)b * HH * ROWLEN;

    // ---- load tile with reflect on h ----
    for (int r = hg; r < HLOAD; r += 4) {
        int hs = h0 - RR + r;
        hs = hs < 0 ? -hs : hs;
        hs = hs > 511 ? 1022 - hs : hs;
        tile[r * FW + col] = src[imgbase + (size_t)hs * ROWLEN + wc0 + col];
    }
    __syncthreads();

    float acc[16];
    #pragma unroll
    for (int a = 0; a < 16; ++a) acc[a] = 0.f;
    #pragma unroll
    for (int j = 0; j < 66; ++j) {
        const float v = tile[(hg * 16 + j) * FW + col];
        #pragma unroll
        for (int a = 0; a < 16; ++a) {
            const int tap = j - a;
            if (tap >= 0 && tap < KK) acc[a] += gw[tap] * v;
        }
    }

    // ---- fused epilogue ----
    #pragma unroll
    for (int a = 0; a < 16; ++a) {
        const int hh = h0 + hg * 16 + a;
        const size_t idx = imgbase + (size_t)hh * ROWLEN + wc0 + col;
        const float x = img[idx];
        if (MODE == 0) {
            const float blur = acc[a];
            blurio[idx] = blur;
            mask8[idx] = (fabsf(x - blur) * 255.0f > 10.0f) ? (unsigned char)1
                                                            : (unsigned char)0;
        } else {
            const float bl = blurio[idx];                       // blur of img
            const float sharp = fminf(fmaxf(x + 0.5f * (x - bl), 0.f), 1.f);
            const float sm = acc[a];                            // soft mask
            blurio[idx] = x + sm * (sharp - x);                 // final output
        }
    }
}

// ---------------------------------------------------------------------------
extern "C" void kernel_launch(void* const* d_in, const int* in_sizes, int n_in,
                              void* d_out, int out_size, void* d_ws, size_t ws_size,
                              hipStream_t stream) {
    (void)in_sizes; (void)n_in; (void)out_size; (void)ws_size;
    const float* img = (const float*)d_in[0];
    const float* k2d = (const float*)d_in[1];
    float* out = (float*)d_out;

    char* ws = (char*)d_ws;
    float* g = (float*)ws;                                       // 51 floats
    float* tbuf = (float*)(ws + 256);                            // 50.33 MB
    unsigned char* mask8 =
        (unsigned char*)(ws + 256 + (size_t)BB * HH * ROWLEN * 4); // 12.58 MB

    const int nrows = BB * HH;            // 8192
    const int nvblk = BB * 8 * 24;        // 3072

    k_weights<<<1, 64, 0, stream>>>(k2d, g);
    // P1: H-blur img -> tbuf
    k_hconv<false><<<nrows, 384, 0, stream>>>((const void*)img, tbuf, g);
    // P2: V-blur tbuf -> blur (into d_out) + mask8
    k_vconv<0><<<nvblk, 256, 0, stream>>>(tbuf, img, out, mask8, g);
    // P3: H-blur mask8 -> tbuf
    k_hconv<true><<<nrows, 384, 0, stream>>>((const void*)mask8, tbuf, g);
    // P4: V-blur tbuf -> soft mask, fused blend -> d_out
    k_vconv<1><<<nvblk, 256, 0, stream>>>(tbuf, img, out, mask8, g);
}

// Round 3
// 171.713 us; speedup vs baseline: 1.2190x; 1.0654x over previous
//
#include <hip/hip_runtime.h>

#define BB 16
#define HH 512
#define WW 512
#define CC 3
#define ROWLEN 1536   // W*C
#define KK 51
#define RR 25

// σ-swizzle for LDS plane layout: bijective, spreads 16-stride windows
// across all 32 banks (17 = 16+1 is coprime to 32).
__device__ __forceinline__ int sig(int x) { return x + (x >> 4); }
#define PSTR 600      // plane stride in floats; sig(561)=596 max used

// ---------------- K0: reduce 2D kernel to 1D weights (g[i] = row sum) -------
__global__ void k_weights(const float* __restrict__ k2d, float* __restrict__ g) {
    int i = threadIdx.x;
    if (i < KK) {
        float s = 0.f;
        for (int j = 0; j < KK; ++j) s += k2d[i * KK + j];
        g[i] = s;
    }
}

// ---------------- H-pass: 51-tap conv along w, per channel ------------------
// 4 rows per block, 384 threads = 12 (row,channel) planes x 32 lanes.
// Planes live σ-swizzled in LDS; each thread computes 16 consecutive pixels
// via a 66-float sliding window: read addr = plane + 17*l + (j + (j>>4)),
// conflict-free (17 coprime 32), per-j offset folds into ds_read immediate.
template<bool U8>
__global__ __launch_bounds__(384, 6) void k_hconv(const void* __restrict__ srcv,
                                                  float* __restrict__ dst,
                                                  const float* __restrict__ gsrc) {
    __shared__ __align__(16) float pl[12][PSTR];
    const int t = threadIdx.x;
    const int row0 = blockIdx.x * 4;             // first of 4 rows (b*512+h)

    float gw[KK];
    #pragma unroll
    for (int i = 0; i < KK; ++i) gw[i] = gsrc[i];   // uniform -> scalar regs

    // ---- load 4 rows, de-interleave: item m -> row m>>7, 12-float group m&127
    #pragma unroll
    for (int it = 0; it < 2; ++it) {
        const int m = t + it * 384;
        if (m < 512) {
            const int r = m >> 7, u = m & 127;       // 12 floats = 4 pixels
            const size_t rb = (size_t)(row0 + r) * ROWLEN;
            if (U8) {
                const unsigned char* s8 = (const unsigned char*)srcv + rb + 12 * u;
                unsigned int ww[3];
                ww[0] = *(const unsigned int*)(s8);
                ww[1] = *(const unsigned int*)(s8 + 4);
                ww[2] = *(const unsigned int*)(s8 + 8);
                #pragma unroll
                for (int i = 0; i < 4; ++i)
                    #pragma unroll
                    for (int c = 0; c < 3; ++c) {
                        const int bidx = 3 * i + c;
                        const float v = (float)((ww[bidx >> 2] >> ((bidx & 3) * 8)) & 0xffu);
                        pl[r * 3 + c][sig(RR + 4 * u + i)] = v;
                    }
            } else {
                const float* sf = (const float*)srcv + rb + 12 * u;
                float f[12];
                *(float4*)&f[0] = *(const float4*)(sf);
                *(float4*)&f[4] = *(const float4*)(sf + 4);
                *(float4*)&f[8] = *(const float4*)(sf + 8);
                #pragma unroll
                for (int i = 0; i < 4; ++i)
                    #pragma unroll
                    for (int c = 0; c < 3; ++c)
                        pl[r * 3 + c][sig(RR + 4 * u + i)] = f[3 * i + c];
            }
        }
    }
    __syncthreads();

    // ---- reflect halos (np.pad 'reflect', excludes edge): 12 planes x 50 ----
    #pragma unroll
    for (int it = 0; it < 2; ++it) {
        const int item = t + it * 384;
        if (item < 600) {
            const int p = item / 50, k = item % 50;
            if (k < 25) pl[p][sig(k)] = pl[p][sig(50 - k)];
            else        pl[p][sig(512 + k)] = pl[p][sig(535 - (k - 25))];
        }
    }
    __syncthreads();

    // ---- compute: 16 consecutive pixels of one (row,channel) per thread ----
    const int p = t >> 5;             // plane 0..11 (wave spans 2 planes)
    const int l = t & 31;             // lane within plane
    const float* base = &pl[p][17 * l];
    float acc[16];
    #pragma unroll
    for (int a = 0; a < 16; ++a) acc[a] = 0.f;
    #pragma unroll
    for (int j = 0; j < 66; ++j) {
        const float v = base[j + (j >> 4)];       // σ(16l+j)
        #pragma unroll
        for (int a = 0; a < 16; ++a) {
            const int tap = j - a;
            if (tap >= 0 && tap < KK) acc[a] += gw[tap] * v;
        }
    }
    const int r = p / 3, c = p % 3;
    const size_t rb = (size_t)(row0 + r) * ROWLEN;
    const int w0 = l << 4;
    #pragma unroll
    for (int a = 0; a < 16; ++a)
        dst[rb + (size_t)(w0 + a) * 3 + c] = acc[a];
}

// ---------------- V-pass: 51-tap conv along h + fused epilogue --------------
// Tile: 64 flat columns x 64 output rows (+2*25 halo). 256 threads =
// 64 cols x 4 h-groups; each thread computes 16 outputs (sliding window).
// MODE 0: blur -> blurio (d_out as scratch), mask -> mask8.
// MODE 1: soft-mask; read img + blur (from blurio), write final to blurio.
#define HC 64
#define FW 64
#define HLOAD 114    // HC + 2*RR

template<int MODE>
__global__ __launch_bounds__(256) void k_vconv(const float* __restrict__ src,
                                               const float* __restrict__ img,
                                               float* blurio,
                                               unsigned char* __restrict__ mask8,
                                               const float* __restrict__ gsrc) {
    __shared__ __align__(16) float tile[HLOAD * FW];
    const int t   = threadIdx.x;
    const int col = t & 63;
    const int hg  = t >> 6;              // 0..3 (wave-uniform)
    const int bid = blockIdx.x;
    const int wcB = bid % 24;
    const int hB  = (bid / 24) & 7;
    const int b   = bid / 192;
    const int wc0 = wcB * 64;
    const int h0  = hB * 64;

    float gw[KK];
    #pragma unroll
    for (int i = 0; i < KK; ++i) gw[i] = gsrc[i];

    const size_t imgbase = (size_t)b * HH * ROWLEN;

    // ---- load tile with reflect on h: float2, 8 rows per iteration ----
    const int c2 = t & 31, rg = t >> 5;
    #pragma unroll
    for (int r0 = 0; r0 < 120; r0 += 8) {
        const int rr = r0 + rg;
        if (rr < HLOAD) {
            int hs = h0 - RR + rr;
            hs = hs < 0 ? -hs : hs;
            hs = hs > 511 ? 1022 - hs : hs;
            const float2 v = *(const float2*)&src[imgbase + (size_t)hs * ROWLEN + wc0 + 2 * c2];
            *(float2*)&tile[rr * FW + 2 * c2] = v;
        }
    }
    __syncthreads();

    float acc[16];
    #pragma unroll
    for (int a = 0; a < 16; ++a) acc[a] = 0.f;
    #pragma unroll
    for (int j = 0; j < 66; ++j) {
        const float v = tile[(hg * 16 + j) * FW + col];
        #pragma unroll
        for (int a = 0; a < 16; ++a) {
            const int tap = j - a;
            if (tap >= 0 && tap < KK) acc[a] += gw[tap] * v;
        }
    }

    // ---- fused epilogue ----
    #pragma unroll
    for (int a = 0; a < 16; ++a) {
        const int hh = h0 + hg * 16 + a;
        const size_t idx = imgbase + (size_t)hh * ROWLEN + wc0 + col;
        const float x = img[idx];
        if (MODE == 0) {
            const float blur = acc[a];
            blurio[idx] = blur;
            mask8[idx] = (fabsf(x - blur) * 255.0f > 10.0f) ? (unsigned char)1
                                                            : (unsigned char)0;
        } else {
            const float bl = blurio[idx];                       // blur of img
            const float sharp = fminf(fmaxf(x + 0.5f * (x - bl), 0.f), 1.f);
            const float sm = acc[a];                            // soft mask
            blurio[idx] = x + sm * (sharp - x);                 // final output
        }
    }
}

// ---------------------------------------------------------------------------
extern "C" void kernel_launch(void* const* d_in, const int* in_sizes, int n_in,
                              void* d_out, int out_size, void* d_ws, size_t ws_size,
                              hipStream_t stream) {
    (void)in_sizes; (void)n_in; (void)out_size; (void)ws_size;
    const float* img = (const float*)d_in[0];
    const float* k2d = (const float*)d_in[1];
    float* out = (float*)d_out;

    char* ws = (char*)d_ws;
    float* g = (float*)ws;                                       // 51 floats
    float* tbuf = (float*)(ws + 256);                            // 50.33 MB
    unsigned char* mask8 =
        (unsigned char*)(ws + 256 + (size_t)BB * HH * ROWLEN * 4); // 12.58 MB

    const int nhblk = BB * HH / 4;        // 2048
    const int nvblk = BB * 8 * 24;        // 3072

    k_weights<<<1, 64, 0, stream>>>(k2d, g);
    // P1: H-blur img -> tbuf
    k_hconv<false><<<nhblk, 384, 0, stream>>>((const void*)img, tbuf, g);
    // P2: V-blur tbuf -> blur (into d_out) + mask8
    k_vconv<0><<<nvblk, 256, 0, stream>>>(tbuf, img, out, mask8, g);
    // P3: H-blur mask8 -> tbuf
    k_hconv<true><<<nhblk, 384, 0, stream>>>((const void*)mask8, tbuf, g);
    // P4: V-blur tbuf -> soft mask, fused blend -> d_out
    k_vconv<1><<<nvblk, 256, 0, stream>>>(tbuf, img, out, mask8, g);
}